// Round 4
// baseline (369.054 us; speedup 1.0000x reference)
//
#include <hip/hip_runtime.h>
#include <hip/hip_bf16.h>
#include <stdint.h>

typedef __attribute__((ext_vector_type(8)))  __bf16 bf16x8;
typedef __attribute__((ext_vector_type(4)))  float  f32x4;
typedef __attribute__((ext_vector_type(16))) float  f32x16;

#define KP 4160   // padded K: 4096 (quantized x) + 32 (lora T) + 32 zeros = 65 tiles of 64

__device__ inline void async_copy16(const void* g, void* l) {
  __builtin_amdgcn_global_load_lds((const __attribute__((address_space(1))) void*)g,
                                   (__attribute__((address_space(3))) void*)l, 16, 0, 0);
}

// ---------------------------------------------------------------------------
// Kernel 1 (FULLY MERGED prep): one launch, three block roles, ZERO
// inter-block dependencies (no Tp round-trip).
//   blocks [0,2048):      quant  — SmoothQuant+NVFP4 -> Ab[:,0:4096] (bit-exact
//                         closed-form level select, verified r3)
//   blocks [2048,10368):  wconv  — w->bf16 Bb[:,0:4096], lora_b->Bb[:,4096:4128],
//                         zeros ->Bb[:,4128:4160)
//   blocks [10368,10624): loraT  — T = x_smoothed @ la^T computed FULL-K per
//                         block (4 waves x 1024-wide K windows, MFMA 16x16x32,
//                         LDS cross-wave reduce) -> bf16 Ab[:,4096:4128] + zeros
// ---------------------------------------------------------------------------
__global__ __launch_bounds__(256) void prep_kernel(
    const float* __restrict__ x, const float* __restrict__ ss,
    const float* __restrict__ w, const float* __restrict__ la,
    const float* __restrict__ lb, __bf16* __restrict__ Ab,
    __bf16* __restrict__ Bb) {
  __shared__ float red[4][16][32];
  int b   = blockIdx.x;
  int tid = threadIdx.x;

  if (b < 2048) {
    // ---- quant: rows [16*(b>>3),+16) x cols [512*(b&7),+512) ----
    int m0 = (b >> 3) << 4;
    int by = b & 7;
    int row = m0 + (tid >> 4);
    int cb0 = tid & 15;
#pragma unroll
    for (int i = 0; i < 2; i++) {
      int col = (by << 9) + ((cb0 + (i << 4)) << 4);
      const float4* xp = (const float4*)(x + ((size_t)row << 12) + col);
      const float4* sp = (const float4*)(ss + col);
      float xs[16];
#pragma unroll
      for (int j = 0; j < 4; j++) {
        float4 xv = xp[j]; float4 sv = sp[j];
        xs[4*j+0] = xv.x * sv.x; xs[4*j+1] = xv.y * sv.y;
        xs[4*j+2] = xv.z * sv.z; xs[4*j+3] = xv.w * sv.w;
      }
      float amax = 0.f;
#pragma unroll
      for (int j = 0; j < 16; j++) amax = fmaxf(amax, fabsf(xs[j]));
      amax = fmaxf(amax, 1e-12f);
      float scale = amax / 6.0f;              // IEEE fp32 divide, same as np
      bf16x8 o0, o1;
#pragma unroll
      for (int j = 0; j < 16; j++) {
        float a  = fabsf(xs[j]);
        float xn = a / scale;                 // IEEE fp32 divide, same as np
        float lvl;
        if (xn < 2.25f) {
          lvl = 0.5f * __builtin_ceilf(__builtin_fmaf(2.0f, xn, -0.5f));
        } else {
          lvl = (xn <= 2.5f) ? 2.0f : (xn <= 3.5f) ? 3.0f
              : (xn <= 5.0f) ? 4.0f : 6.0f;
        }
        float mag = lvl * scale;
        float q = (xs[j] > 0.f) ? mag : ((xs[j] < 0.f) ? -mag : 0.f);
        if (j < 8) o0[j] = (__bf16)q; else o1[j-8] = (__bf16)q;
      }
      __bf16* dst = Ab + (size_t)row * KP + col;
      *(bf16x8*)dst = o0;
      *(bf16x8*)(dst + 8) = o1;
    }
  } else if (b < 10368) {
    // ---- wconv: w -> Bb bf16 + lora_b cols + zero pad (520 groups/row) ----
    int id  = (b - 2048) * 256 + tid;         // < 4096*520
    int row = id / 520;
    int g   = id - row * 520;
    bf16x8 v;
    if (g < 512) {
      const float4* wp = (const float4*)(w + ((size_t)row << 12) + (g << 3));
      float4 a = wp[0], bb = wp[1];
      v[0]=(__bf16)a.x;  v[1]=(__bf16)a.y;  v[2]=(__bf16)a.z;  v[3]=(__bf16)a.w;
      v[4]=(__bf16)bb.x; v[5]=(__bf16)bb.y; v[6]=(__bf16)bb.z; v[7]=(__bf16)bb.w;
    } else if (g < 516) {
      const float* p = lb + (size_t)row * 32 + ((g - 512) << 3);
#pragma unroll
      for (int j = 0; j < 8; j++) v[j] = (__bf16)p[j];
    } else {
#pragma unroll
      for (int j = 0; j < 8; j++) v[j] = (__bf16)0.f;
    }
    *(bf16x8*)(Bb + (size_t)row * KP + ((size_t)g << 3)) = v;
  } else {
    // ---- loraT: rows [16j,+16), full K=4096; wave k-window 1024 ----
    int j16  = (b - 10368) << 4;
    int wave = tid >> 6, lane = tid & 63;
    int lrow = lane & 15, kg = lane >> 4;
    f32x4 acc0 = {0.f,0.f,0.f,0.f}, acc1 = {0.f,0.f,0.f,0.f};
    const float* xrow = x + ((size_t)(j16 + lrow) << 12);
    const float* a0   = la + ((size_t)lrow << 12);
    const float* a1   = a0 + (16 << 12);
#pragma unroll 4
    for (int k0 = 0; k0 < 32; k0++) {
      int kk = (wave << 10) + (k0 << 5) + (kg << 3);
      float xv[8], sv[8], v0[8], v1[8];
      *(float4*)&xv[0] = *(const float4*)(xrow + kk);
      *(float4*)&xv[4] = *(const float4*)(xrow + kk + 4);
      *(float4*)&sv[0] = *(const float4*)(ss + kk);
      *(float4*)&sv[4] = *(const float4*)(ss + kk + 4);
      *(float4*)&v0[0] = *(const float4*)(a0 + kk);
      *(float4*)&v0[4] = *(const float4*)(a0 + kk + 4);
      *(float4*)&v1[0] = *(const float4*)(a1 + kk);
      *(float4*)&v1[4] = *(const float4*)(a1 + kk + 4);
      bf16x8 af, b0, b1;
#pragma unroll
      for (int q = 0; q < 8; q++) {
        af[q] = (__bf16)(xv[q] * sv[q]);
        b0[q] = (__bf16)v0[q];
        b1[q] = (__bf16)v1[q];
      }
      acc0 = __builtin_amdgcn_mfma_f32_16x16x32_bf16(af, b0, acc0, 0, 0, 0);
      acc1 = __builtin_amdgcn_mfma_f32_16x16x32_bf16(af, b1, acc1, 0, 0, 0);
    }
#pragma unroll
    for (int r = 0; r < 4; r++) {
      red[wave][kg*4 + r][lrow]      = acc0[r];   // verified layout (r1-r5)
      red[wave][kg*4 + r][16 + lrow] = acc1[r];
    }
    __syncthreads();
    for (int o = tid; o < 512; o += 256) {
      int rr = o >> 5, cc = o & 31;
      float s = red[0][rr][cc] + red[1][rr][cc] + red[2][rr][cc] + red[3][rr][cc];
      __bf16* dst = Ab + (size_t)(j16 + rr) * KP + 4096;
      dst[cc]      = (__bf16)s;
      dst[32 + cc] = (__bf16)0.f;
    }
  }
}

// ---------------------------------------------------------------------------
// Kernel 2: 256x256 8-phase GEMM with 32x32x16 MFMA (17% cheaper pipe cycles
// than 16x16x32: 2382 vs 2075 TF ubench; half the issue slots).
// Per wave: 128x64 out = 4m x 2n frags of 32x32, f32x16 acc each.
// A/B frag (r0-verified): m(n)=lane&31, k=(lane>>5)*8+j.  C/D (m74/m101):
// col=lane&31, row=(reg&3)+8*(reg>>2)+4*(lane>>5).
// LDS layout (same st_16x32 family as r1, staging identical): element (r,k)
// of a 128x64 half at sub(r>>4)*2048 + (k>>5)*1024 + [(r&15)*64+(k&31)*2]
// ^ ((r&8)<<2).  32-row frag reads hit 64 distinct 16B slots -> conflict-free.
// Phases p0..p3 compute tile t (buf0) k-steps ks0..3; B frags for all 4 ks
// prefetched in p0/p1 (B reads complete by p1's MFMA lgkm wait) so B-halves
// can be restaged p2/p3; A restaged p4/p5; gates WVM(4) at p3/p7 (r1-proven
// schedule, 2 loads/phase, keep newest 4 in flight).
// ---------------------------------------------------------------------------
#define GBAR() __builtin_amdgcn_s_barrier()
#define PRI1() __builtin_amdgcn_s_setprio(1)
#define PRI0() __builtin_amdgcn_s_setprio(0)
#define WVM(n) asm volatile("s_waitcnt vmcnt(" #n ")" ::: "memory")

#define STG(srcb, dstb, bb, h, t) do {                                         \
    const __bf16* _s = (srcb) + (size_t)(h) * (128 * (size_t)KP)               \
                              + ((size_t)(t) << 6);                            \
    char* _d = (dstb) + ((bb) << 15) + ((h) << 14);                            \
    async_copy16(_s, _d);                                                      \
    async_copy16(_s + 32, _d + 1024);                                          \
  } while (0)

#define KOFF(KS) ((((KS) >> 1) << 10) + ((((KS) & 1) << 5) ^ sx))

#define RD_A(base, KS) do { _Pragma("unroll")                                  \
  for (int mf = 0; mf < 4; mf++)                                               \
    af[mf] = *(const bf16x8*)((base) + (mf << 12) + KOFF(KS)); } while (0)

#define RD_B(base, KS) do {                                                    \
    Br[0*4 + (KS)] = *(const bf16x8*)((base) + KOFF(KS));                      \
    Br[1*4 + (KS)] = *(const bf16x8*)((base) + 4096 + KOFF(KS)); } while (0)

#define MM8(KS) do { _Pragma("unroll")                                         \
  for (int mf = 0; mf < 4; mf++) _Pragma("unroll")                             \
  for (int nf = 0; nf < 2; nf++)                                               \
    acc[mf][nf] = __builtin_amdgcn_mfma_f32_32x32x16_bf16(                     \
        af[mf], Br[nf*4 + (KS)], acc[mf][nf], 0, 0, 0); } while (0)

__global__ __launch_bounds__(512, 2) void gemm_kernel(const __bf16* __restrict__ A,
                                                      const __bf16* __restrict__ B,
                                                      const float* __restrict__ bias,
                                                      float* __restrict__ C) {
  extern __shared__ char lds[];                // 131072 B: A[2x32K] | B[2x32K]
  const int tid  = threadIdx.x;
  const int w    = tid >> 6, lane = tid & 63;
  const int ln31 = lane & 31, kg2 = lane >> 5;
  const int wm   = w >> 2, wn = w & 3;
  const int bid  = blockIdx.x;
  const int sbid = ((bid & 7) << 5) | (bid >> 3);  // XCD swizzle (256%8==0)
  const int bm   = sbid >> 4, bn = sbid & 15;
  const size_t m0 = (size_t)bm << 8, n0 = (size_t)bn << 8;

  // staging source (per-thread, inverse-swizzled; identical map to r1)
  const int rr = (w << 4) + (lane >> 2);
  const int kk = ((lane & 3) ^ (((lane >> 5) & 1) << 1)) << 3;
  const __bf16* aS = A + (m0 + rr) * (size_t)KP + kk;
  const __bf16* bS = B + (n0 + rr) * (size_t)KP + kk;
  char* dA = lds + (w << 11);
  char* dB = lds + 65536 + (w << 11);

  // fragment read pointers
  const int sx = (lane & 8) << 2;              // row-XOR swizzle bit
  const int cA = ((ln31 >> 4) << 11) + ((ln31 & 15) << 6) + (kg2 << 4);
  const int cB = ((((wn & 1) << 2) + (ln31 >> 4)) << 11)
               + ((ln31 & 15) << 6) + (kg2 << 4);
  const char* pA0 = lds + (wm << 14) + cA;
  const char* pA1 = pA0 + 32768;
  const char* pB0 = lds + 65536 + ((wn >> 1) << 14) + cB;
  const char* pB1 = pB0 + 32768;

  bf16x8 af[4], Br[8];
  f32x16 acc[4][2];
#pragma unroll
  for (int i = 0; i < 4; i++)
#pragma unroll
    for (int j = 0; j < 2; j++)
#pragma unroll
      for (int q = 0; q < 16; q++) acc[i][j][q] = 0.f;

  // prologue: tile0 -> buf0, tile1.B -> buf1; t0 landed, t1.B in flight.
  STG(bS, dB, 0, 0, 0); STG(bS, dB, 0, 1, 0);
  STG(aS, dA, 0, 0, 0); STG(aS, dA, 0, 1, 0);
  STG(bS, dB, 1, 0, 1); STG(bS, dB, 1, 1, 1);
  WVM(4);
  GBAR();

#pragma unroll 1
  for (int i = 0; i < 32; i++) {
    const int t1 = 2*i + 1, t2 = 2*i + 2;
    int t3 = 2*i + 3; if (t3 > 64) t3 = 64;    // stray (unread) restage, in-bounds
    // ---- tile 2i (buf0) ----
    STG(aS, dA, 1, 0, t1);                     // p0
    RD_B(pB0, 0); RD_B(pB0, 1); RD_A(pA0, 0);
    PRI1(); MM8(0); PRI0();
    GBAR();
    STG(aS, dA, 1, 1, t1);                     // p1
    RD_B(pB0, 2); RD_B(pB0, 3); RD_A(pA0, 1);
    PRI1(); MM8(1); PRI0();
    GBAR();
    STG(bS, dB, 0, 0, t2);                     // p2  (buf0.B reads done by p1)
    RD_A(pA0, 2);
    PRI1(); MM8(2); PRI0();
    GBAR();
    STG(bS, dB, 0, 1, t2);                     // p3
    RD_A(pA0, 3);
    PRI1(); MM8(3); PRI0();
    WVM(4);                                    // gate: buf1 (t1) landed
    GBAR();
    // ---- tile 2i+1 (buf1) ----
    STG(aS, dA, 0, 0, t2);                     // p4  (buf0.A reads done by p3)
    RD_B(pB1, 0); RD_B(pB1, 1); RD_A(pA1, 0);
    PRI1(); MM8(0); PRI0();
    GBAR();
    STG(aS, dA, 0, 1, t2);                     // p5
    RD_B(pB1, 2); RD_B(pB1, 3); RD_A(pA1, 1);
    PRI1(); MM8(1); PRI0();
    GBAR();
    STG(bS, dB, 1, 0, t3);                     // p6  (buf1.B reads done by p5)
    RD_A(pA1, 2);
    PRI1(); MM8(2); PRI0();
    GBAR();
    STG(bS, dB, 1, 1, t3);                     // p7
    RD_A(pA1, 3);
    PRI1(); MM8(3); PRI0();
    WVM(4);                                    // gate: buf0 (t2) landed
    GBAR();
  }

  // epilogue: tile 64 (buf0), staged during last iter p2-p5, gated at p7.
  RD_B(pB0, 0); RD_B(pB0, 1); RD_B(pB0, 2); RD_B(pB0, 3);
  RD_A(pA0, 0); PRI1(); MM8(0); PRI0();
  RD_A(pA0, 1); PRI1(); MM8(1); PRI0();
  RD_A(pA0, 2); PRI1(); MM8(2); PRI0();
  RD_A(pA0, 3); PRI1(); MM8(3); PRI0();

  // C-write: + bias, fp32.  col=lane&31, row=(q&3)+8*(q>>2)+4*kg2.
  const int    colb = (int)n0 + (wn << 6) + ln31;
  const size_t rowb = m0 + ((size_t)wm << 7) + (kg2 << 2);
#pragma unroll
  for (int nf = 0; nf < 2; nf++) {
    const int col = colb + (nf << 5);
    const float bv = bias[col];
#pragma unroll
    for (int mf = 0; mf < 4; mf++) {
      const size_t r0 = rowb + ((size_t)mf << 5);
#pragma unroll
      for (int q = 0; q < 16; q++) {
        const size_t row = r0 + (q & 3) + ((q >> 2) << 3);
        C[row * 4096 + col] = acc[mf][nf][q] + bv;
      }
    }
  }
}

extern "C" void kernel_launch(void* const* d_in, const int* in_sizes, int n_in,
                              void* d_out, int out_size, void* d_ws, size_t ws_size,
                              hipStream_t stream) {
  const float* x    = (const float*)d_in[0];   // [2,2048,4096]
  const float* ss   = (const float*)d_in[1];   // [4096]
  const float* w    = (const float*)d_in[2];   // [4096,4096]
  const float* la   = (const float*)d_in[3];   // [32,4096]
  const float* lb   = (const float*)d_in[4];   // [4096,32]
  const float* bias = (const float*)d_in[5];   // [4096]
  float* out = (float*)d_out;                  // [2,2048,4096] fp32

  __bf16* Ab = (__bf16*)d_ws;                  // [4096, 4160] bf16  (34.1 MB)
  __bf16* Bb = Ab + (size_t)4096 * KP;         // [4096, 4160] bf16  (34.1 MB)

  static bool s_attr = false;
  if (!s_attr) {                               // config call, not a stream op
    hipFuncSetAttribute((const void*)gemm_kernel,
                        hipFuncAttributeMaxDynamicSharedMemorySize, 131072);
    s_attr = true;
  }

  prep_kernel<<<10624, 256, 0, stream>>>(x, ss, w, la, lb, Ab, Bb);
  gemm_kernel<<<256, 512, 131072, stream>>>(Ab, Bb, bias, out);
}

// Round 5
// 368.578 us; speedup vs baseline: 1.0013x; 1.0013x over previous
//
#include <hip/hip_runtime.h>
#include <hip/hip_bf16.h>
#include <stdint.h>

typedef __attribute__((ext_vector_type(8)))  __bf16 bf16x8;
typedef __attribute__((ext_vector_type(4)))  float  f32x4;

#define KP 4224   // padded K: 4096 (quantized x) + 32 (lora T) + 96 zeros = 66 tiles of 64

__device__ inline void async_copy16(const void* g, void* l) {
  __builtin_amdgcn_global_load_lds((const __attribute__((address_space(1))) void*)g,
                                   (__attribute__((address_space(3))) void*)l, 16, 0, 0);
}

// ---------------------------------------------------------------------------
// Kernel 1 (FULLY MERGED prep, r4 structure verified 145us; KP-4224 pads):
//   blocks [0,2048):      quant  — SmoothQuant+NVFP4 -> Ab[:,0:4096]
//   blocks [2048,10496):  wconv  — w->bf16 Bb[:,0:4096], lora_b->Bb[:,4096:4128],
//                         zeros->Bb[:,4128:4224)
//   blocks [10496,10752): loraT  — T = x_smoothed @ la^T full-K per block ->
//                         bf16 Ab[:,4096:4128] + zeros Ab[:,4128:4224)
// ---------------------------------------------------------------------------
__global__ __launch_bounds__(256) void prep_kernel(
    const float* __restrict__ x, const float* __restrict__ ss,
    const float* __restrict__ w, const float* __restrict__ la,
    const float* __restrict__ lb, __bf16* __restrict__ Ab,
    __bf16* __restrict__ Bb) {
  __shared__ float red[4][16][32];
  int b   = blockIdx.x;
  int tid = threadIdx.x;

  if (b < 2048) {
    // ---- quant: rows [16*(b>>3),+16) x cols [512*(b&7),+512) ----
    int m0 = (b >> 3) << 4;
    int by = b & 7;
    int row = m0 + (tid >> 4);
    int cb0 = tid & 15;
#pragma unroll
    for (int i = 0; i < 2; i++) {
      int col = (by << 9) + ((cb0 + (i << 4)) << 4);
      const float4* xp = (const float4*)(x + ((size_t)row << 12) + col);
      const float4* sp = (const float4*)(ss + col);
      float xs[16];
#pragma unroll
      for (int j = 0; j < 4; j++) {
        float4 xv = xp[j]; float4 sv = sp[j];
        xs[4*j+0] = xv.x * sv.x; xs[4*j+1] = xv.y * sv.y;
        xs[4*j+2] = xv.z * sv.z; xs[4*j+3] = xv.w * sv.w;
      }
      float amax = 0.f;
#pragma unroll
      for (int j = 0; j < 16; j++) amax = fmaxf(amax, fabsf(xs[j]));
      amax = fmaxf(amax, 1e-12f);
      float scale = amax / 6.0f;              // IEEE fp32 divide, same as np
      bf16x8 o0, o1;
#pragma unroll
      for (int j = 0; j < 16; j++) {
        float a  = fabsf(xs[j]);
        float xn = a / scale;                 // IEEE fp32 divide, same as np
        float lvl;
        if (xn < 2.25f) {
          // 0.5-grid nearest, tie -> lower (== argmin first-on-tie, verified r3)
          lvl = 0.5f * __builtin_ceilf(__builtin_fmaf(2.0f, xn, -0.5f));
        } else {
          lvl = (xn <= 2.5f) ? 2.0f : (xn <= 3.5f) ? 3.0f
              : (xn <= 5.0f) ? 4.0f : 6.0f;
        }
        float mag = lvl * scale;
        float q = (xs[j] > 0.f) ? mag : ((xs[j] < 0.f) ? -mag : 0.f);
        if (j < 8) o0[j] = (__bf16)q; else o1[j-8] = (__bf16)q;
      }
      __bf16* dst = Ab + (size_t)row * KP + col;
      *(bf16x8*)dst = o0;
      *(bf16x8*)(dst + 8) = o1;
    }
  } else if (b < 10496) {
    // ---- wconv: w -> Bb bf16 + lora_b cols + zero pad (528 groups/row) ----
    int id  = (b - 2048) * 256 + tid;         // < 4096*528
    int row = id / 528;
    int g   = id - row * 528;
    bf16x8 v;
    if (g < 512) {
      const float4* wp = (const float4*)(w + ((size_t)row << 12) + (g << 3));
      float4 a = wp[0], bb = wp[1];
      v[0]=(__bf16)a.x;  v[1]=(__bf16)a.y;  v[2]=(__bf16)a.z;  v[3]=(__bf16)a.w;
      v[4]=(__bf16)bb.x; v[5]=(__bf16)bb.y; v[6]=(__bf16)bb.z; v[7]=(__bf16)bb.w;
    } else if (g < 516) {
      const float* p = lb + (size_t)row * 32 + ((g - 512) << 3);
#pragma unroll
      for (int j = 0; j < 8; j++) v[j] = (__bf16)p[j];
    } else {
#pragma unroll
      for (int j = 0; j < 8; j++) v[j] = (__bf16)0.f;
    }
    *(bf16x8*)(Bb + (size_t)row * KP + ((size_t)g << 3)) = v;
  } else {
    // ---- loraT: rows [16j,+16), full K=4096; wave k-window 1024 ----
    int j16  = (b - 10496) << 4;
    int wave = tid >> 6, lane = tid & 63;
    int lrow = lane & 15, kg = lane >> 4;
    f32x4 acc0 = {0.f,0.f,0.f,0.f}, acc1 = {0.f,0.f,0.f,0.f};
    const float* xrow = x + ((size_t)(j16 + lrow) << 12);
    const float* a0   = la + ((size_t)lrow << 12);
    const float* a1   = a0 + (16 << 12);
#pragma unroll 4
    for (int k0 = 0; k0 < 32; k0++) {
      int kk = (wave << 10) + (k0 << 5) + (kg << 3);
      float xv[8], sv[8], v0[8], v1[8];
      *(float4*)&xv[0] = *(const float4*)(xrow + kk);
      *(float4*)&xv[4] = *(const float4*)(xrow + kk + 4);
      *(float4*)&sv[0] = *(const float4*)(ss + kk);
      *(float4*)&sv[4] = *(const float4*)(ss + kk + 4);
      *(float4*)&v0[0] = *(const float4*)(a0 + kk);
      *(float4*)&v0[4] = *(const float4*)(a0 + kk + 4);
      *(float4*)&v1[0] = *(const float4*)(a1 + kk);
      *(float4*)&v1[4] = *(const float4*)(a1 + kk + 4);
      bf16x8 af, b0, b1;
#pragma unroll
      for (int q = 0; q < 8; q++) {
        af[q] = (__bf16)(xv[q] * sv[q]);
        b0[q] = (__bf16)v0[q];
        b1[q] = (__bf16)v1[q];
      }
      acc0 = __builtin_amdgcn_mfma_f32_16x16x32_bf16(af, b0, acc0, 0, 0, 0);
      acc1 = __builtin_amdgcn_mfma_f32_16x16x32_bf16(af, b1, acc1, 0, 0, 0);
    }
#pragma unroll
    for (int r = 0; r < 4; r++) {
      red[wave][kg*4 + r][lrow]      = acc0[r];   // verified layout (r1-r5)
      red[wave][kg*4 + r][16 + lrow] = acc1[r];
    }
    __syncthreads();
    for (int o = tid; o < 512; o += 256) {
      int rr = o >> 5, cc = o & 31;
      float s = red[0][rr][cc] + red[1][rr][cc] + red[2][rr][cc] + red[3][rr][cc];
      __bf16* dst = Ab + (size_t)(j16 + rr) * KP + 4096;
      dst[cc]      = (__bf16)s;
      dst[32 + cc] = (__bf16)0.f;
      dst[64 + cc] = (__bf16)0.f;
      dst[96 + cc] = (__bf16)0.f;
    }
  }
}

// ---------------------------------------------------------------------------
// Kernel 2: r3 gemm VERBATIM (measured 126us, MfmaUtil 48%, 0 bank conflicts).
// 256x256 8-phase GEMM, register-double-buffered frags, one barrier/phase,
// counted vmcnt gates at p2/p6.  16x16x32 bf16 MFMA.
// ---------------------------------------------------------------------------
#define GBAR() __builtin_amdgcn_s_barrier()
#define PRI1() __builtin_amdgcn_s_setprio(1)
#define PRI0() __builtin_amdgcn_s_setprio(0)
#define WVM(n) asm volatile("s_waitcnt vmcnt(" #n ")" ::: "memory")

#define STG(srcb, dstb, bb, h, t) do {                                         \
    const __bf16* _s = (srcb) + (size_t)(h) * (128 * (size_t)KP)               \
                              + ((size_t)(t) << 6);                            \
    char* _d = (dstb) + ((bb) << 15) + ((h) << 14);                            \
    async_copy16(_s, _d);                                                      \
    async_copy16(_s + 32, _d + 1024);                                          \
  } while (0)

#define LD8(dst, p, off) do { _Pragma("unroll")                                \
  for (int u = 0; u < 8; u++)                                                  \
    dst[u] = *(const bf16x8*)((p) + (((off) + u) << 10)); } while (0)

#define LD4(dst, p, off) do { _Pragma("unroll")                                \
  for (int u = 0; u < 4; u++)                                                  \
    dst[u] = *(const bf16x8*)((p) + (((off) + u) << 10)); } while (0)

#define MMQ(Ar, Br, MFB, NFB) do {                                             \
  _Pragma("unroll") for (int mf = 0; mf < 4; mf++)                             \
  _Pragma("unroll") for (int nf = 0; nf < 2; nf++)                             \
  _Pragma("unroll") for (int ks = 0; ks < 2; ks++)                             \
    acc[(MFB)+mf][(NFB)+nf] = __builtin_amdgcn_mfma_f32_16x16x32_bf16(         \
        Ar[mf*2+ks], Br[nf*2+ks], acc[(MFB)+mf][(NFB)+nf], 0, 0, 0);           \
  } while (0)

__global__ __launch_bounds__(512, 2) void gemm_kernel(const __bf16* __restrict__ A,
                                                      const __bf16* __restrict__ B,
                                                      const float* __restrict__ bias,
                                                      float* __restrict__ C) {
  extern __shared__ char lds[];                // 131072 B: [A0|A1|B0|B1] 32K each
  const int tid  = threadIdx.x;
  const int w    = tid >> 6, lane = tid & 63;
  const int ln15 = lane & 15, kg = lane >> 4;
  const int wm   = w >> 2, wn = w & 3;
  const int bid  = blockIdx.x;
  const int sbid = ((bid & 7) << 5) | (bid >> 3);  // XCD swizzle (256%8==0, bijective)
  const int bm   = sbid >> 4, bn = sbid & 15;
  const size_t m0 = (size_t)bm << 8, n0 = (size_t)bn << 8;

  // staging source (per-thread, inverse-swizzled)
  const int rr = (w << 4) + (lane >> 2);
  const int kk = ((lane & 3) ^ (((lane >> 5) & 1) << 1)) << 3;
  const __bf16* aS = A + (m0 + rr) * (size_t)KP + kk;
  const __bf16* bS = B + (n0 + rr) * (size_t)KP + kk;
  char* dA = lds + (w << 11);                  // wave-uniform LDS dest bases
  char* dB = lds + 65536 + (w << 11);

  // fragment read pointers (swizzled)
  int inner = (ln15 << 6) + (kg << 4);
  inner ^= (ln15 & 8) << 2;                    // ^32 when row&8
  const char* pA0 = lds + (wm << 14) + inner;
  const char* pA1 = pA0 + 32768;
  const char* pB0 = lds + 65536 + (wn << 13) + inner;
  const char* pB1 = pB0 + 32768;

  bf16x8 Ax[8], Ay[8], Bg0[4], Bg1[4];
  f32x4 acc[8][4];
#pragma unroll
  for (int i = 0; i < 8; i++)
#pragma unroll
    for (int j = 0; j < 4; j++) acc[i][j] = (f32x4){0.f, 0.f, 0.f, 0.f};

  // prologue: tile0 -> buf0, tile1.B -> buf1; then preload first frags.
  STG(bS, dB, 0, 0, 0); STG(bS, dB, 0, 1, 0);
  STG(aS, dA, 0, 0, 0); STG(aS, dA, 0, 1, 0);
  STG(bS, dB, 1, 0, 1); STG(bS, dB, 1, 1, 1);
  WVM(4);
  GBAR();
  LD8(Ax, pA0, 0); LD4(Bg0, pB0, 0);

#pragma unroll 1
  for (int i = 0; i < 32; i++) {
    const int t1 = 2*i + 1, t2 = 2*i + 2, t3 = 2*i + 3;
    // ---- tile 2i (buf0) ----
    GBAR();                                    // p0
    STG(aS, dA, 1, 0, t1);
    LD8(Ay, pA0, 8); LD4(Bg1, pB0, 4);
    PRI1(); MMQ(Ax, Bg0, 0, 0); PRI0();
    GBAR();                                    // p1
    STG(aS, dA, 1, 1, t1);
    PRI1(); MMQ(Ax, Bg1, 0, 2); PRI0();
    GBAR();                                    // p2
    STG(bS, dB, 0, 0, t2);
    PRI1(); MMQ(Ay, Bg0, 4, 0); PRI0();
    WVM(2);                                    // gate: buf1 (t1.A + t1.B) landed
    GBAR();                                    // p3
    STG(bS, dB, 0, 1, t2);
    LD8(Ax, pA1, 0); LD4(Bg0, pB1, 0);
    PRI1(); MMQ(Ay, Bg1, 4, 2); PRI0();
    // ---- tile 2i+1 (buf1) ----
    GBAR();                                    // p4
    STG(aS, dA, 0, 0, t2);
    LD8(Ay, pA1, 8); LD4(Bg1, pB1, 4);
    PRI1(); MMQ(Ax, Bg0, 0, 0); PRI0();
    GBAR();                                    // p5
    STG(aS, dA, 0, 1, t2);
    PRI1(); MMQ(Ax, Bg1, 0, 2); PRI0();
    GBAR();                                    // p6
    STG(bS, dB, 1, 0, t3);
    PRI1(); MMQ(Ay, Bg0, 4, 0); PRI0();
    WVM(2);                                    // gate: buf0 (t2) landed
    GBAR();                                    // p7
    STG(bS, dB, 1, 1, t3);
    LD8(Ax, pA0, 0); LD4(Bg0, pB0, 0);
    PRI1(); MMQ(Ay, Bg1, 4, 2); PRI0();
  }

  // epilogue: tiles 64 (buf0) and 65 (buf1); only t65.A still needs staging.
  GBAR();                                      // e0
  STG(aS, dA, 1, 0, 65);
  LD8(Ay, pA0, 8); LD4(Bg1, pB0, 4);
  PRI1(); MMQ(Ax, Bg0, 0, 0); PRI0();
  GBAR();                                      // e1
  STG(aS, dA, 1, 1, 65);
  PRI1(); MMQ(Ax, Bg1, 0, 2); PRI0();
  GBAR();                                      // e2
  PRI1(); MMQ(Ay, Bg0, 4, 0); PRI0();
  WVM(0);                                      // gate: t65.A + t65.B landed
  GBAR();                                      // e3
  LD8(Ax, pA1, 0); LD4(Bg0, pB1, 0);
  PRI1(); MMQ(Ay, Bg1, 4, 2); PRI0();
  GBAR();                                      // e4
  LD8(Ay, pA1, 8); LD4(Bg1, pB1, 4);
  PRI1(); MMQ(Ax, Bg0, 0, 0); PRI0();
  GBAR();                                      // e5
  PRI1(); MMQ(Ax, Bg1, 0, 2); PRI0();
  GBAR();                                      // e6
  PRI1(); MMQ(Ay, Bg0, 4, 0); PRI0();
  GBAR();                                      // e7
  PRI1(); MMQ(Ay, Bg1, 4, 2); PRI0();

  // epilogue: + bias, fp32 store.  C/D layout: col=lane&15, row=(lane>>4)*4+q.
  const int    colb = (int)n0 + (wn << 6) + ln15;
  const size_t rowb = m0 + ((size_t)wm << 7) + (kg << 2);
#pragma unroll
  for (int nf = 0; nf < 4; nf++) {
    const int col = colb + (nf << 4);
    const float bv = bias[col];
#pragma unroll
    for (int mf = 0; mf < 8; mf++) {
      const size_t r0 = rowb + ((size_t)mf << 4);
#pragma unroll
      for (int q = 0; q < 4; q++)
        C[(r0 + q) * 4096 + col] = acc[mf][nf][q] + bv;
    }
  }
}

extern "C" void kernel_launch(void* const* d_in, const int* in_sizes, int n_in,
                              void* d_out, int out_size, void* d_ws, size_t ws_size,
                              hipStream_t stream) {
  const float* x    = (const float*)d_in[0];   // [2,2048,4096]
  const float* ss   = (const float*)d_in[1];   // [4096]
  const float* w    = (const float*)d_in[2];   // [4096,4096]
  const float* la   = (const float*)d_in[3];   // [32,4096]
  const float* lb   = (const float*)d_in[4];   // [4096,32]
  const float* bias = (const float*)d_in[5];   // [4096]
  float* out = (float*)d_out;                  // [2,2048,4096] fp32

  __bf16* Ab = (__bf16*)d_ws;                  // [4096, 4224] bf16  (34.6 MB)
  __bf16* Bb = Ab + (size_t)4096 * KP;         // [4096, 4224] bf16  (34.6 MB)

  static bool s_attr = false;
  if (!s_attr) {                               // config call, not a stream op
    hipFuncSetAttribute((const void*)gemm_kernel,
                        hipFuncAttributeMaxDynamicSharedMemorySize, 131072);
    s_attr = true;
  }

  prep_kernel<<<10752, 256, 0, stream>>>(x, ss, w, la, lb, Ab, Bb);
  gemm_kernel<<<256, 512, 131072, stream>>>(Ab, Bb, bias, out);
}

// Round 8
// 315.368 us; speedup vs baseline: 1.1702x; 1.1687x over previous
//
#include <hip/hip_runtime.h>
#include <hip/hip_bf16.h>
#include <stdint.h>

typedef __attribute__((ext_vector_type(8)))  __bf16 bf16x8;
typedef __attribute__((ext_vector_type(4)))  float  f32x4;
typedef __attribute__((ext_vector_type(16))) float  f32x16;

#define KP 4160   // padded K: 4096 (quantized x) + 32 (lora T) + 32 zeros = 65 tiles of 64

__device__ inline void async_copy16(const void* g, void* l) {
  __builtin_amdgcn_global_load_lds((const __attribute__((address_space(1))) void*)g,
                                   (__attribute__((address_space(3))) void*)l, 16, 0, 0);
}

// ---------------------------------------------------------------------------
// Kernel 1 (r3-verified structure, 310us config): per-block window =
// rows [16*bx,+16) x cols [512*by,+512), grid (256,8).
// Part A: SmoothQuant + NVFP4 fake-quant -> bf16 Ab[:,0:4096] (closed-form
// bit-exact level select, verified r3).  Part B: LoRA partial T via MFMA ->
// Tp[by][4096][32] (fp32, lives in d_out scratch).
// VALU-bound first kernel also absorbs the prior iteration's C-writeback
// drain (r4/r5 post-mortem: merging it with the streaming wconv cost +58us
// in the timed graph despite a faster profiled dur).
// ---------------------------------------------------------------------------
__global__ __launch_bounds__(256) void fused_quant_lora_kernel(
    const float* __restrict__ x, const float* __restrict__ ss,
    const float* __restrict__ la, __bf16* __restrict__ Ab,
    float* __restrict__ Tp) {
  __shared__ float red[4][16][32];
  int tid  = threadIdx.x;
  int m0   = blockIdx.x << 4;                 // 16-row strip
  int by   = blockIdx.y;                      // 512-col k-chunk

  // ---- Part A: quant ----
  {
    int row = m0 + (tid >> 4);
    int cb0 = tid & 15;
#pragma unroll
    for (int i = 0; i < 2; i++) {
      int col = (by << 9) + ((cb0 + (i << 4)) << 4);
      const float4* xp = (const float4*)(x + ((size_t)row << 12) + col);
      const float4* sp = (const float4*)(ss + col);
      float xs[16];
#pragma unroll
      for (int j = 0; j < 4; j++) {
        float4 xv = xp[j]; float4 sv = sp[j];
        xs[4*j+0] = xv.x * sv.x; xs[4*j+1] = xv.y * sv.y;
        xs[4*j+2] = xv.z * sv.z; xs[4*j+3] = xv.w * sv.w;
      }
      float amax = 0.f;
#pragma unroll
      for (int j = 0; j < 16; j++) amax = fmaxf(amax, fabsf(xs[j]));
      amax = fmaxf(amax, 1e-12f);
      float scale = amax / 6.0f;              // IEEE fp32 divide, same as np
      bf16x8 o0, o1;
#pragma unroll
      for (int j = 0; j < 16; j++) {
        float a  = fabsf(xs[j]);
        float xn = a / scale;                 // IEEE fp32 divide, same as np
        float lvl;
        if (xn < 2.25f) {
          // 0.5-grid nearest, tie -> lower (== argmin first-on-tie, verified r3)
          lvl = 0.5f * __builtin_ceilf(__builtin_fmaf(2.0f, xn, -0.5f));
        } else {
          lvl = (xn <= 2.5f) ? 2.0f : (xn <= 3.5f) ? 3.0f
              : (xn <= 5.0f) ? 4.0f : 6.0f;
        }
        float mag = lvl * scale;
        float q = (xs[j] > 0.f) ? mag : ((xs[j] < 0.f) ? -mag : 0.f);
        if (j < 8) o0[j] = (__bf16)q; else o1[j-8] = (__bf16)q;
      }
      __bf16* dst = Ab + (size_t)row * KP + col;
      *(bf16x8*)dst = o0;
      *(bf16x8*)(dst + 8) = o1;
    }
  }

  // ---- Part B: LoRA partial via MFMA (verified fragment layout) ----
  {
    int wave = tid >> 6, lane = tid & 63;
    int lrow = lane & 15, kg = lane >> 4;
    int kbase = (by << 9) + (wave << 7);      // 128-wide window per wave
    f32x4 acc0 = {0.f,0.f,0.f,0.f}, acc1 = {0.f,0.f,0.f,0.f};
    const float* xrow = x + ((size_t)(m0 + lrow) << 12);
    const float* a0   = la + ((size_t)lrow << 12);
    const float* a1   = a0 + (16 << 12);
#pragma unroll
    for (int k0 = 0; k0 < 128; k0 += 32) {
      int kk = kbase + k0 + (kg << 3);
      float xv[8], sv[8], v0[8], v1[8];
      *(float4*)&xv[0] = *(const float4*)(xrow + kk);
      *(float4*)&xv[4] = *(const float4*)(xrow + kk + 4);
      *(float4*)&sv[0] = *(const float4*)(ss + kk);
      *(float4*)&sv[4] = *(const float4*)(ss + kk + 4);
      *(float4*)&v0[0] = *(const float4*)(a0 + kk);
      *(float4*)&v0[4] = *(const float4*)(a0 + kk + 4);
      *(float4*)&v1[0] = *(const float4*)(a1 + kk);
      *(float4*)&v1[4] = *(const float4*)(a1 + kk + 4);
      bf16x8 af, b0, b1;
#pragma unroll
      for (int j = 0; j < 8; j++) {
        af[j] = (__bf16)(xv[j] * sv[j]);
        b0[j] = (__bf16)v0[j];
        b1[j] = (__bf16)v1[j];
      }
      acc0 = __builtin_amdgcn_mfma_f32_16x16x32_bf16(af, b0, acc0, 0, 0, 0);
      acc1 = __builtin_amdgcn_mfma_f32_16x16x32_bf16(af, b1, acc1, 0, 0, 0);
    }
#pragma unroll
    for (int r = 0; r < 4; r++) {
      red[wave][kg*4 + r][lrow]      = acc0[r];   // verified layout (r1-r5)
      red[wave][kg*4 + r][16 + lrow] = acc1[r];
    }
    __syncthreads();
    for (int o = tid; o < 512; o += 256) {
      int rr = o >> 5, cc = o & 31;
      float s = red[0][rr][cc] + red[1][rr][cc] + red[2][rr][cc] + red[3][rr][cc];
      Tp[((size_t)by * 4096 + m0 + rr) * 32 + cc] = s;
    }
  }
}

// ---------------------------------------------------------------------------
// Kernel 2 (MERGED wconv + lora_fix, r3-verified structure, KP-4160 consts):
// blocks [0,8320): w -> bf16 Bb[:,0:4096], lora_b -> Bb[:,4096:4128],
// zeros -> Bb[:,4128:4160).  Blocks [8320,8832): sum the 8 Tp partials ->
// bf16 T into Ab[:,4096:4128] + zero pad 4128:4160.
// ---------------------------------------------------------------------------
__global__ __launch_bounds__(256) void wconv_fix_kernel(const float* __restrict__ w,
                                                        const float* __restrict__ lb,
                                                        const float* __restrict__ Tp,
                                                        __bf16* __restrict__ Bb,
                                                        __bf16* __restrict__ Ab) {
  int b = blockIdx.x;
  if (b < 8320) {
    int id  = b * 256 + threadIdx.x;          // < 4096*520
    int row = id / 520;
    int g   = id - row * 520;
    bf16x8 v;
    if (g < 512) {
      const float4* wp = (const float4*)(w + ((size_t)row << 12) + (g << 3));
      float4 a = wp[0], bb = wp[1];
      v[0]=(__bf16)a.x;  v[1]=(__bf16)a.y;  v[2]=(__bf16)a.z;  v[3]=(__bf16)a.w;
      v[4]=(__bf16)bb.x; v[5]=(__bf16)bb.y; v[6]=(__bf16)bb.z; v[7]=(__bf16)bb.w;
    } else if (g < 516) {
      const float* p = lb + (size_t)row * 32 + ((g - 512) << 3);
#pragma unroll
      for (int j = 0; j < 8; j++) v[j] = (__bf16)p[j];
    } else {
#pragma unroll
      for (int j = 0; j < 8; j++) v[j] = (__bf16)0.f;
    }
    *(bf16x8*)(Bb + (size_t)row * KP + ((size_t)g << 3)) = v;
  } else {
    int id  = (b - 8320) * 256 + threadIdx.x; // < 4096*32
    int row = id >> 5, cc = id & 31;
    float s = 0.f;
#pragma unroll
    for (int kc = 0; kc < 8; kc++)
      s += Tp[((size_t)kc * 4096 + row) * 32 + cc];
    __bf16* dst = Ab + (size_t)row * KP + 4096;
    dst[cc]      = (__bf16)s;
    dst[32 + cc] = (__bf16)0.f;
  }
}

// ---------------------------------------------------------------------------
// Kernel 3: 256x256 8-phase GEMM with 32x32x16 MFMA (r4 code verbatim —
// exonerated by r4/r5 post-mortem: it profiled <142.8us; the r4 regression
// was the merged-prep timed-run artifact, not this kernel).
// 15% cheaper pipe cycles than 16x16x32 (2382 vs 2075 TF ubench); half the
// MFMA issue slots.  Per wave: 128x64 out = 4m x 2n frags of 32x32.
// A/B frag: m(n)=lane&31, k=(lane>>5)*8+j.  C/D (m74/m101): col=lane&31,
// row=(q&3)+8*(q>>2)+4*(lane>>5).  This round verifies the 32-row frag-read
// bank-conflict derivation via SQ_LDS_BANK_CONFLICT.
// ---------------------------------------------------------------------------
#define GBAR() __builtin_amdgcn_s_barrier()
#define PRI1() __builtin_amdgcn_s_setprio(1)
#define PRI0() __builtin_amdgcn_s_setprio(0)
#define WVM(n) asm volatile("s_waitcnt vmcnt(" #n ")" ::: "memory")

#define STG(srcb, dstb, bb, h, t) do {                                         \
    const __bf16* _s = (srcb) + (size_t)(h) * (128 * (size_t)KP)               \
                              + ((size_t)(t) << 6);                            \
    char* _d = (dstb) + ((bb) << 15) + ((h) << 14);                            \
    async_copy16(_s, _d);                                                      \
    async_copy16(_s + 32, _d + 1024);                                          \
  } while (0)

#define KOFF(KS) ((((KS) >> 1) << 10) + ((((KS) & 1) << 5) ^ sx))

#define RD_A(base, KS) do { _Pragma("unroll")                                  \
  for (int mf = 0; mf < 4; mf++)                                               \
    af[mf] = *(const bf16x8*)((base) + (mf << 12) + KOFF(KS)); } while (0)

#define RD_B(base, KS) do {                                                    \
    Br[0*4 + (KS)] = *(const bf16x8*)((base) + KOFF(KS));                      \
    Br[1*4 + (KS)] = *(const bf16x8*)((base) + 4096 + KOFF(KS)); } while (0)

#define MM8(KS) do { _Pragma("unroll")                                         \
  for (int mf = 0; mf < 4; mf++) _Pragma("unroll")                             \
  for (int nf = 0; nf < 2; nf++)                                               \
    acc[mf][nf] = __builtin_amdgcn_mfma_f32_32x32x16_bf16(                     \
        af[mf], Br[nf*4 + (KS)], acc[mf][nf], 0, 0, 0); } while (0)

__global__ __launch_bounds__(512, 2) void gemm_kernel(const __bf16* __restrict__ A,
                                                      const __bf16* __restrict__ B,
                                                      const float* __restrict__ bias,
                                                      float* __restrict__ C) {
  extern __shared__ char lds[];                // 131072 B: A[2x32K] | B[2x32K]
  const int tid  = threadIdx.x;
  const int w    = tid >> 6, lane = tid & 63;
  const int ln31 = lane & 31, kg2 = lane >> 5;
  const int wm   = w >> 2, wn = w & 3;
  const int bid  = blockIdx.x;
  const int sbid = ((bid & 7) << 5) | (bid >> 3);  // XCD swizzle (256%8==0)
  const int bm   = sbid >> 4, bn = sbid & 15;
  const size_t m0 = (size_t)bm << 8, n0 = (size_t)bn << 8;

  // staging source (per-thread, inverse-swizzled; identical map to r1)
  const int rr = (w << 4) + (lane >> 2);
  const int kk = ((lane & 3) ^ (((lane >> 5) & 1) << 1)) << 3;
  const __bf16* aS = A + (m0 + rr) * (size_t)KP + kk;
  const __bf16* bS = B + (n0 + rr) * (size_t)KP + kk;
  char* dA = lds + (w << 11);
  char* dB = lds + 65536 + (w << 11);

  // fragment read pointers
  const int sx = (lane & 8) << 2;              // row-XOR swizzle bit
  const int cA = ((ln31 >> 4) << 11) + ((ln31 & 15) << 6) + (kg2 << 4);
  const int cB = ((((wn & 1) << 2) + (ln31 >> 4)) << 11)
               + ((ln31 & 15) << 6) + (kg2 << 4);
  const char* pA0 = lds + (wm << 14) + cA;
  const char* pA1 = pA0 + 32768;
  const char* pB0 = lds + 65536 + ((wn >> 1) << 14) + cB;
  const char* pB1 = pB0 + 32768;

  bf16x8 af[4], Br[8];
  f32x16 acc[4][2];
#pragma unroll
  for (int i = 0; i < 4; i++)
#pragma unroll
    for (int j = 0; j < 2; j++)
#pragma unroll
      for (int q = 0; q < 16; q++) acc[i][j][q] = 0.f;

  // prologue: tile0 -> buf0, tile1.B -> buf1; t0 landed, t1.B in flight.
  STG(bS, dB, 0, 0, 0); STG(bS, dB, 0, 1, 0);
  STG(aS, dA, 0, 0, 0); STG(aS, dA, 0, 1, 0);
  STG(bS, dB, 1, 0, 1); STG(bS, dB, 1, 1, 1);
  WVM(4);
  GBAR();

#pragma unroll 1
  for (int i = 0; i < 32; i++) {
    const int t1 = 2*i + 1, t2 = 2*i + 2;
    int t3 = 2*i + 3; if (t3 > 64) t3 = 64;    // stray (unread) restage, in-bounds
    // ---- tile 2i (buf0) ----
    STG(aS, dA, 1, 0, t1);                     // p0
    RD_B(pB0, 0); RD_B(pB0, 1); RD_A(pA0, 0);
    PRI1(); MM8(0); PRI0();
    GBAR();
    STG(aS, dA, 1, 1, t1);                     // p1
    RD_B(pB0, 2); RD_B(pB0, 3); RD_A(pA0, 1);
    PRI1(); MM8(1); PRI0();
    GBAR();
    STG(bS, dB, 0, 0, t2);                     // p2  (buf0.B reads done by p1)
    RD_A(pA0, 2);
    PRI1(); MM8(2); PRI0();
    GBAR();
    STG(bS, dB, 0, 1, t2);                     // p3
    RD_A(pA0, 3);
    PRI1(); MM8(3); PRI0();
    WVM(4);                                    // gate: buf1 (t1) landed
    GBAR();
    // ---- tile 2i+1 (buf1) ----
    STG(aS, dA, 0, 0, t2);                     // p4  (buf0.A reads done by p3)
    RD_B(pB1, 0); RD_B(pB1, 1); RD_A(pA1, 0);
    PRI1(); MM8(0); PRI0();
    GBAR();
    STG(aS, dA, 0, 1, t2);                     // p5
    RD_B(pB1, 2); RD_B(pB1, 3); RD_A(pA1, 1);
    PRI1(); MM8(1); PRI0();
    GBAR();
    STG(bS, dB, 1, 0, t3);                     // p6  (buf1.B reads done by p5)
    RD_A(pA1, 2);
    PRI1(); MM8(2); PRI0();
    GBAR();
    STG(bS, dB, 1, 1, t3);                     // p7
    RD_A(pA1, 3);
    PRI1(); MM8(3); PRI0();
    WVM(4);                                    // gate: buf0 (t2) landed
    GBAR();
  }

  // epilogue: tile 64 (buf0), staged during last iter p2-p5, gated at p7.
  RD_B(pB0, 0); RD_B(pB0, 1); RD_B(pB0, 2); RD_B(pB0, 3);
  RD_A(pA0, 0); PRI1(); MM8(0); PRI0();
  RD_A(pA0, 1); PRI1(); MM8(1); PRI0();
  RD_A(pA0, 2); PRI1(); MM8(2); PRI0();
  RD_A(pA0, 3); PRI1(); MM8(3); PRI0();

  // C-write: + bias, fp32.  col=lane&31, row=(q&3)+8*(q>>2)+4*kg2.
  const int    colb = (int)n0 + (wn << 6) + ln31;
  const size_t rowb = m0 + ((size_t)wm << 7) + (kg2 << 2);
#pragma unroll
  for (int nf = 0; nf < 2; nf++) {
    const int col = colb + (nf << 5);
    const float bv = bias[col];
#pragma unroll
    for (int mf = 0; mf < 4; mf++) {
      const size_t r0 = rowb + ((size_t)mf << 5);
#pragma unroll
      for (int q = 0; q < 16; q++) {
        const size_t row = r0 + (q & 3) + ((q >> 2) << 3);
        C[row * 4096 + col] = acc[mf][nf][q] + bv;
      }
    }
  }
}

extern "C" void kernel_launch(void* const* d_in, const int* in_sizes, int n_in,
                              void* d_out, int out_size, void* d_ws, size_t ws_size,
                              hipStream_t stream) {
  const float* x    = (const float*)d_in[0];   // [2,2048,4096]
  const float* ss   = (const float*)d_in[1];   // [4096]
  const float* w    = (const float*)d_in[2];   // [4096,4096]
  const float* la   = (const float*)d_in[3];   // [32,4096]
  const float* lb   = (const float*)d_in[4];   // [4096,32]
  const float* bias = (const float*)d_in[5];   // [4096]
  float* out = (float*)d_out;                  // [2,2048,4096] fp32

  __bf16* Ab = (__bf16*)d_ws;                  // [4096, 4160] bf16  (34.1 MB)
  __bf16* Bb = Ab + (size_t)4096 * KP;         // [4096, 4160] bf16  (34.1 MB)
  // Tp lives in d_out scratch: 8*4096*32*4 = 4 MB << 67 MB.  Consumed by
  // wconv_fix, then d_out fully overwritten by gemm.
  float* Tp = out;                             // [8][4096][32] fp32 (4 MB)

  static bool s_attr = false;
  if (!s_attr) {                               // config call, not a stream op
    hipFuncSetAttribute((const void*)gemm_kernel,
                        hipFuncAttributeMaxDynamicSharedMemorySize, 131072);
    s_attr = true;
  }

  fused_quant_lora_kernel<<<dim3(256, 8), 256, 0, stream>>>(x, ss, la, Ab, Tp);
  wconv_fix_kernel<<<8832, 256, 0, stream>>>(w, lb, Tp, Bb, Ab);
  gemm_kernel<<<256, 512, 131072, stream>>>(Ab, Bb, bias, out);
}

// Round 9
// 311.946 us; speedup vs baseline: 1.1831x; 1.0110x over previous
//
#include <hip/hip_runtime.h>
#include <hip/hip_bf16.h>
#include <stdint.h>

typedef __attribute__((ext_vector_type(8)))  __bf16 bf16x8;
typedef __attribute__((ext_vector_type(4)))  float  f32x4;
typedef __attribute__((ext_vector_type(16))) float  f32x16;

#define KP 4160   // padded K: 4096 (quantized x) + 32 (lora T) + 32 zeros = 65 tiles of 64

__device__ inline void async_copy16(const void* g, void* l) {
  __builtin_amdgcn_global_load_lds((const __attribute__((address_space(1))) void*)g,
                                   (__attribute__((address_space(3))) void*)l, 16, 0, 0);
}

// ---------------------------------------------------------------------------
// Kernel 1 (r3-verified structure): rows [16*bx,+16) x cols [512*by,+512),
// grid (256,8).  Part A: SmoothQuant + NVFP4 fake-quant -> bf16 Ab[:,0:4096]
// (closed-form bit-exact level select, verified r3).  Part B: LoRA partial T
// via MFMA -> Tp[by][4096][32] (fp32, in d_out scratch).
// ---------------------------------------------------------------------------
__global__ __launch_bounds__(256) void fused_quant_lora_kernel(
    const float* __restrict__ x, const float* __restrict__ ss,
    const float* __restrict__ la, __bf16* __restrict__ Ab,
    float* __restrict__ Tp) {
  __shared__ float red[4][16][32];
  int tid  = threadIdx.x;
  int m0   = blockIdx.x << 4;                 // 16-row strip
  int by   = blockIdx.y;                      // 512-col k-chunk

  // ---- Part A: quant ----
  {
    int row = m0 + (tid >> 4);
    int cb0 = tid & 15;
#pragma unroll
    for (int i = 0; i < 2; i++) {
      int col = (by << 9) + ((cb0 + (i << 4)) << 4);
      const float4* xp = (const float4*)(x + ((size_t)row << 12) + col);
      const float4* sp = (const float4*)(ss + col);
      float xs[16];
#pragma unroll
      for (int j = 0; j < 4; j++) {
        float4 xv = xp[j]; float4 sv = sp[j];
        xs[4*j+0] = xv.x * sv.x; xs[4*j+1] = xv.y * sv.y;
        xs[4*j+2] = xv.z * sv.z; xs[4*j+3] = xv.w * sv.w;
      }
      float amax = 0.f;
#pragma unroll
      for (int j = 0; j < 16; j++) amax = fmaxf(amax, fabsf(xs[j]));
      amax = fmaxf(amax, 1e-12f);
      float scale = amax / 6.0f;              // IEEE fp32 divide, same as np
      bf16x8 o0, o1;
#pragma unroll
      for (int j = 0; j < 16; j++) {
        float a  = fabsf(xs[j]);
        float xn = a / scale;                 // IEEE fp32 divide, same as np
        float lvl;
        if (xn < 2.25f) {
          // 0.5-grid nearest, tie -> lower (== argmin first-on-tie, verified r3)
          lvl = 0.5f * __builtin_ceilf(__builtin_fmaf(2.0f, xn, -0.5f));
        } else {
          lvl = (xn <= 2.5f) ? 2.0f : (xn <= 3.5f) ? 3.0f
              : (xn <= 5.0f) ? 4.0f : 6.0f;
        }
        float mag = lvl * scale;
        float q = (xs[j] > 0.f) ? mag : ((xs[j] < 0.f) ? -mag : 0.f);
        if (j < 8) o0[j] = (__bf16)q; else o1[j-8] = (__bf16)q;
      }
      __bf16* dst = Ab + (size_t)row * KP + col;
      *(bf16x8*)dst = o0;
      *(bf16x8*)(dst + 8) = o1;
    }
  }

  // ---- Part B: LoRA partial via MFMA (verified fragment layout) ----
  {
    int wave = tid >> 6, lane = tid & 63;
    int lrow = lane & 15, kg = lane >> 4;
    int kbase = (by << 9) + (wave << 7);      // 128-wide window per wave
    f32x4 acc0 = {0.f,0.f,0.f,0.f}, acc1 = {0.f,0.f,0.f,0.f};
    const float* xrow = x + ((size_t)(m0 + lrow) << 12);
    const float* a0   = la + ((size_t)lrow << 12);
    const float* a1   = a0 + (16 << 12);
#pragma unroll
    for (int k0 = 0; k0 < 128; k0 += 32) {
      int kk = kbase + k0 + (kg << 3);
      float xv[8], sv[8], v0[8], v1[8];
      *(float4*)&xv[0] = *(const float4*)(xrow + kk);
      *(float4*)&xv[4] = *(const float4*)(xrow + kk + 4);
      *(float4*)&sv[0] = *(const float4*)(ss + kk);
      *(float4*)&sv[4] = *(const float4*)(ss + kk + 4);
      *(float4*)&v0[0] = *(const float4*)(a0 + kk);
      *(float4*)&v0[4] = *(const float4*)(a0 + kk + 4);
      *(float4*)&v1[0] = *(const float4*)(a1 + kk);
      *(float4*)&v1[4] = *(const float4*)(a1 + kk + 4);
      bf16x8 af, b0, b1;
#pragma unroll
      for (int j = 0; j < 8; j++) {
        af[j] = (__bf16)(xv[j] * sv[j]);
        b0[j] = (__bf16)v0[j];
        b1[j] = (__bf16)v1[j];
      }
      acc0 = __builtin_amdgcn_mfma_f32_16x16x32_bf16(af, b0, acc0, 0, 0, 0);
      acc1 = __builtin_amdgcn_mfma_f32_16x16x32_bf16(af, b1, acc1, 0, 0, 0);
    }
#pragma unroll
    for (int r = 0; r < 4; r++) {
      red[wave][kg*4 + r][lrow]      = acc0[r];   // verified layout (r1-r5)
      red[wave][kg*4 + r][16 + lrow] = acc1[r];
    }
    __syncthreads();
    for (int o = tid; o < 512; o += 256) {
      int rr = o >> 5, cc = o & 31;
      float s = red[0][rr][cc] + red[1][rr][cc] + red[2][rr][cc] + red[3][rr][cc];
      Tp[((size_t)by * 4096 + m0 + rr) * 32 + cc] = s;
    }
  }
}

// ---------------------------------------------------------------------------
// Kernel 2 (MERGED wconv + lora_fix, r3-verified structure):
// blocks [0,8320): w -> bf16 Bb[:,0:4096], lora_b -> Bb[:,4096:4128],
// zeros -> Bb[:,4128:4160).  Blocks [8320,8832): sum the 8 Tp partials ->
// bf16 T into Ab[:,4096:4128] + zero pad 4128:4160.
// ---------------------------------------------------------------------------
__global__ __launch_bounds__(256) void wconv_fix_kernel(const float* __restrict__ w,
                                                        const float* __restrict__ lb,
                                                        const float* __restrict__ Tp,
                                                        __bf16* __restrict__ Bb,
                                                        __bf16* __restrict__ Ab) {
  int b = blockIdx.x;
  if (b < 8320) {
    int id  = b * 256 + threadIdx.x;          // < 4096*520
    int row = id / 520;
    int g   = id - row * 520;
    bf16x8 v;
    if (g < 512) {
      const float4* wp = (const float4*)(w + ((size_t)row << 12) + (g << 3));
      float4 a = wp[0], bb = wp[1];
      v[0]=(__bf16)a.x;  v[1]=(__bf16)a.y;  v[2]=(__bf16)a.z;  v[3]=(__bf16)a.w;
      v[4]=(__bf16)bb.x; v[5]=(__bf16)bb.y; v[6]=(__bf16)bb.z; v[7]=(__bf16)bb.w;
    } else if (g < 516) {
      const float* p = lb + (size_t)row * 32 + ((g - 512) << 3);
#pragma unroll
      for (int j = 0; j < 8; j++) v[j] = (__bf16)p[j];
    } else {
#pragma unroll
      for (int j = 0; j < 8; j++) v[j] = (__bf16)0.f;
    }
    *(bf16x8*)(Bb + (size_t)row * KP + ((size_t)g << 3)) = v;
  } else {
    int id  = (b - 8320) * 256 + threadIdx.x; // < 4096*32
    int row = id >> 5, cc = id & 31;
    float s = 0.f;
#pragma unroll
    for (int kc = 0; kc < 8; kc++)
      s += Tp[((size_t)kc * 4096 + row) * 32 + cc];
    __bf16* dst = Ab + (size_t)row * KP + 4096;
    dst[cc]      = (__bf16)s;
    dst[32 + cc] = (__bf16)0.f;
  }
}

// ---------------------------------------------------------------------------
// Kernel 3: 256x256 8-phase GEMM, 32x32x16 MFMA, NOW with half-wave
// bank-spread fix.  r8 post-mortem: 1.28e7 bank conflicts because kg2 =
// lane>>5 aligns the 16B k-slot split with the SIMD-32 half-wave boundary —
// each half-wave hit only 16 of 32 banks ({0,32,64,96} resp {16,48,80,112}
// byte%128).  Fix: extra XOR of byte bit-4 with row bit-4 — rows 16-31 of
// each half shift one 16B slot, so each half-wave covers all 8 slots x 4
// lanes = all 32 banks (the 16x16 kernels' pattern, measured 0 conflicts).
// Applied BOTH sides (rule #21): staging source kk ^= (w&1)<<3 (row bit4 ==
// wave bit0, wave-uniform -> linear gload_lds dest unchanged); frag read
// (kg2<<4) ^ ((ln31>>4)&1)<<4.  Bijective per-chunk -> bit-exact.
// ---------------------------------------------------------------------------
#define GBAR() __builtin_amdgcn_s_barrier()
#define PRI1() __builtin_amdgcn_s_setprio(1)
#define PRI0() __builtin_amdgcn_s_setprio(0)
#define WVM(n) asm volatile("s_waitcnt vmcnt(" #n ")" ::: "memory")

#define STG(srcb, dstb, bb, h, t) do {                                         \
    const __bf16* _s = (srcb) + (size_t)(h) * (128 * (size_t)KP)               \
                              + ((size_t)(t) << 6);                            \
    char* _d = (dstb) + ((bb) << 15) + ((h) << 14);                            \
    async_copy16(_s, _d);                                                      \
    async_copy16(_s + 32, _d + 1024);                                          \
  } while (0)

#define KOFF(KS) ((((KS) >> 1) << 10) + ((((KS) & 1) << 5) ^ sx))

#define RD_A(base, KS) do { _Pragma("unroll")                                  \
  for (int mf = 0; mf < 4; mf++)                                               \
    af[mf] = *(const bf16x8*)((base) + (mf << 12) + KOFF(KS)); } while (0)

#define RD_B(base, KS) do {                                                    \
    Br[0*4 + (KS)] = *(const bf16x8*)((base) + KOFF(KS));                      \
    Br[1*4 + (KS)] = *(const bf16x8*)((base) + 4096 + KOFF(KS)); } while (0)

#define MM8(KS) do { _Pragma("unroll")                                         \
  for (int mf = 0; mf < 4; mf++) _Pragma("unroll")                             \
  for (int nf = 0; nf < 2; nf++)                                               \
    acc[mf][nf] = __builtin_amdgcn_mfma_f32_32x32x16_bf16(                     \
        af[mf], Br[nf*4 + (KS)], acc[mf][nf], 0, 0, 0); } while (0)

__global__ __launch_bounds__(512, 2) void gemm_kernel(const __bf16* __restrict__ A,
                                                      const __bf16* __restrict__ B,
                                                      const float* __restrict__ bias,
                                                      float* __restrict__ C) {
  extern __shared__ char lds[];                // 131072 B: A[2x32K] | B[2x32K]
  const int tid  = threadIdx.x;
  const int w    = tid >> 6, lane = tid & 63;
  const int ln31 = lane & 31, kg2 = lane >> 5;
  const int wm   = w >> 2, wn = w & 3;
  const int bid  = blockIdx.x;
  const int sbid = ((bid & 7) << 5) | (bid >> 3);  // XCD swizzle (256%8==0)
  const int bm   = sbid >> 4, bn = sbid & 15;
  const size_t m0 = (size_t)bm << 8, n0 = (size_t)bn << 8;

  // staging source (per-thread, inverse-swizzled).  NEW: ^ (w&1) applies the
  // row-bit4 16B-slot XOR (row bit4 == wave bit0 for all staged rows).
  const int rr = (w << 4) + (lane >> 2);
  const int kk = ((lane & 3) ^ (((lane >> 5) & 1) << 1) ^ (w & 1)) << 3;
  const __bf16* aS = A + (m0 + rr) * (size_t)KP + kk;
  const __bf16* bS = B + (n0 + rr) * (size_t)KP + kk;
  char* dA = lds + (w << 11);
  char* dB = lds + 65536 + (w << 11);

  // fragment read pointers.  NEW: k-slot bit4 = kg2 ^ row-bit4.
  const int sx  = (lane & 8) << 2;             // row-bit3 XOR (byte bit5)
  const int k16 = ((kg2 ^ ((ln31 >> 4) & 1)) << 4);  // row-bit4 XOR (byte bit4)
  const int cA = ((ln31 >> 4) << 11) + ((ln31 & 15) << 6) + k16;
  const int cB = ((((wn & 1) << 2) + (ln31 >> 4)) << 11)
               + ((ln31 & 15) << 6) + k16;
  const char* pA0 = lds + (wm << 14) + cA;
  const char* pA1 = pA0 + 32768;
  const char* pB0 = lds + 65536 + ((wn >> 1) << 14) + cB;
  const char* pB1 = pB0 + 32768;

  bf16x8 af[4], Br[8];
  f32x16 acc[4][2];
#pragma unroll
  for (int i = 0; i < 4; i++)
#pragma unroll
    for (int j = 0; j < 2; j++)
#pragma unroll
      for (int q = 0; q < 16; q++) acc[i][j][q] = 0.f;

  // prologue: tile0 -> buf0, tile1.B -> buf1; t0 landed, t1.B in flight.
  STG(bS, dB, 0, 0, 0); STG(bS, dB, 0, 1, 0);
  STG(aS, dA, 0, 0, 0); STG(aS, dA, 0, 1, 0);
  STG(bS, dB, 1, 0, 1); STG(bS, dB, 1, 1, 1);
  WVM(4);
  GBAR();

#pragma unroll 1
  for (int i = 0; i < 32; i++) {
    const int t1 = 2*i + 1, t2 = 2*i + 2;
    int t3 = 2*i + 3; if (t3 > 64) t3 = 64;    // stray (unread) restage, in-bounds
    // ---- tile 2i (buf0) ----
    STG(aS, dA, 1, 0, t1);                     // p0
    RD_B(pB0, 0); RD_B(pB0, 1); RD_A(pA0, 0);
    PRI1(); MM8(0); PRI0();
    GBAR();
    STG(aS, dA, 1, 1, t1);                     // p1
    RD_B(pB0, 2); RD_B(pB0, 3); RD_A(pA0, 1);
    PRI1(); MM8(1); PRI0();
    GBAR();
    STG(bS, dB, 0, 0, t2);                     // p2  (buf0.B reads done by p1)
    RD_A(pA0, 2);
    PRI1(); MM8(2); PRI0();
    GBAR();
    STG(bS, dB, 0, 1, t2);                     // p3
    RD_A(pA0, 3);
    PRI1(); MM8(3); PRI0();
    WVM(4);                                    // gate: buf1 (t1) landed
    GBAR();
    // ---- tile 2i+1 (buf1) ----
    STG(aS, dA, 0, 0, t2);                     // p4  (buf0.A reads done by p3)
    RD_B(pB1, 0); RD_B(pB1, 1); RD_A(pA1, 0);
    PRI1(); MM8(0); PRI0();
    GBAR();
    STG(aS, dA, 0, 1, t2);                     // p5
    RD_B(pB1, 2); RD_B(pB1, 3); RD_A(pA1, 1);
    PRI1(); MM8(1); PRI0();
    GBAR();
    STG(bS, dB, 1, 0, t3);                     // p6  (buf1.B reads done by p5)
    RD_A(pA1, 2);
    PRI1(); MM8(2); PRI0();
    GBAR();
    STG(bS, dB, 1, 1, t3);                     // p7
    RD_A(pA1, 3);
    PRI1(); MM8(3); PRI0();
    WVM(4);                                    // gate: buf0 (t2) landed
    GBAR();
  }

  // epilogue: tile 64 (buf0), staged during last iter p2-p5, gated at p7.
  RD_B(pB0, 0); RD_B(pB0, 1); RD_B(pB0, 2); RD_B(pB0, 3);
  RD_A(pA0, 0); PRI1(); MM8(0); PRI0();
  RD_A(pA0, 1); PRI1(); MM8(1); PRI0();
  RD_A(pA0, 2); PRI1(); MM8(2); PRI0();
  RD_A(pA0, 3); PRI1(); MM8(3); PRI0();

  // C-write: + bias, fp32.  col=lane&31, row=(q&3)+8*(q>>2)+4*kg2.
  const int    colb = (int)n0 + (wn << 6) + ln31;
  const size_t rowb = m0 + ((size_t)wm << 7) + (kg2 << 2);
#pragma unroll
  for (int nf = 0; nf < 2; nf++) {
    const int col = colb + (nf << 5);
    const float bv = bias[col];
#pragma unroll
    for (int mf = 0; mf < 4; mf++) {
      const size_t r0 = rowb + ((size_t)mf << 5);
#pragma unroll
      for (int q = 0; q < 16; q++) {
        const size_t row = r0 + (q & 3) + ((q >> 2) << 3);
        C[row * 4096 + col] = acc[mf][nf][q] + bv;
      }
    }
  }
}

extern "C" void kernel_launch(void* const* d_in, const int* in_sizes, int n_in,
                              void* d_out, int out_size, void* d_ws, size_t ws_size,
                              hipStream_t stream) {
  const float* x    = (const float*)d_in[0];   // [2,2048,4096]
  const float* ss   = (const float*)d_in[1];   // [4096]
  const float* w    = (const float*)d_in[2];   // [4096,4096]
  const float* la   = (const float*)d_in[3];   // [32,4096]
  const float* lb   = (const float*)d_in[4];   // [4096,32]
  const float* bias = (const float*)d_in[5];   // [4096]
  float* out = (float*)d_out;                  // [2,2048,4096] fp32

  __bf16* Ab = (__bf16*)d_ws;                  // [4096, 4160] bf16  (34.1 MB)
  __bf16* Bb = Ab + (size_t)4096 * KP;         // [4096, 4160] bf16  (34.1 MB)
  // Tp lives in d_out scratch: 8*4096*32*4 = 4 MB << 67 MB.  Consumed by
  // wconv_fix, then d_out fully overwritten by gemm.
  float* Tp = out;                             // [8][4096][32] fp32 (4 MB)

  static bool s_attr = false;
  if (!s_attr) {                               // config call, not a stream op
    hipFuncSetAttribute((const void*)gemm_kernel,
                        hipFuncAttributeMaxDynamicSharedMemorySize, 131072);
    s_attr = true;
  }

  fused_quant_lora_kernel<<<dim3(256, 8), 256, 0, stream>>>(x, ss, la, Ab, Tp);
  wconv_fix_kernel<<<8832, 256, 0, stream>>>(w, lb, Tp, Bb, Ab);
  gemm_kernel<<<256, 512, 131072, stream>>>(Ab, Bb, bias, out);
}